// Round 7
// baseline (289.074 us; speedup 1.0000x reference)
//
#include <hip/hip_runtime.h>

#define DIM   256
#define HW_   1024
#define NROWS 32768
#define KEMB  4096

// ---------------- ws layout ----------------
// [0,       131072)  int    idx[32768]
// [131072,  262144)  float  S[32768]     (fallback path only)
// [262144,  278528)  float  E[4096]
// [278528,  278536)  double loss_sum
// [278536,  278540)  int    done
// [278592,  409664)  int    cnt[32768]   (unused on filter path)
// [540736,  1589312) int    cand[32768][8] (unused on filter path)
// [1589312, 3686464) short  ebuf[1048576]  (bf16, 16x16-frag-major, 2 MB)
#define WS_S_OFF    131072
#define WS_E_OFF    262144
#define WS_LOSS_OFF 278528
#define WS_DONE_OFF 278536
#define WS_CNT_OFF  278592
#define WS_CAND_OFF 540736
#define WS_EBUF_OFF 1589312
#define WS_NEEDED   3686464
#define RESCUE_W    1.5e-4f

typedef __attribute__((ext_vector_type(8))) short bf16x8;
typedef __attribute__((ext_vector_type(4))) float f32x4;

__device__ __forceinline__ unsigned short f2bf(float v) {
  unsigned u = __float_as_uint(v);
  return (unsigned short)((u + 0x7FFFu + ((u >> 16) & 1u)) >> 16);
}

// ---------- numpy-pairwise row sums of squares ----------
__device__ __forceinline__ float np_sumsq_128(const float* q, int stride) {
#pragma clang fp contract(off)
  float r[8];
#pragma unroll
  for (int i = 0; i < 8; ++i) { float v = q[i * stride]; r[i] = v * v; }
  for (int blk = 8; blk < 128; blk += 8) {
#pragma unroll
    for (int i = 0; i < 8; ++i) {
      float v = q[(blk + i) * stride];
      float sq = v * v;
      r[i] = r[i] + sq;
    }
  }
  return ((r[0] + r[1]) + (r[2] + r[3])) + ((r[4] + r[5]) + (r[6] + r[7]));
}

// ---------- prep v2: init + E norms (+S only on fallback path) + pack ------
__global__ __launch_bounds__(256) void prep_kernel(
    const float* __restrict__ z, const float* __restrict__ emb,
    float* __restrict__ S, float* __restrict__ E, short* __restrict__ ebuf,
    double* __restrict__ loss_sum, int* __restrict__ done, int do_filter) {
#pragma clang fp contract(off)
  if (blockIdx.x < 144) {
    int t = blockIdx.x * 256 + threadIdx.x;
    if (t == 0) { loss_sum[0] = 0.0; done[0] = 0; }
    if (t < NROWS) {
      if (!do_filter) {
        int b = t >> 10, hw = t & 1023;
        const float* p = z + (size_t)b * (DIM * HW_) + hw;
        float s0 = np_sumsq_128(p, HW_);
        float s1 = np_sumsq_128(p + 128 * HW_, HW_);
        S[t] = s0 + s1;
      }
    } else if (t < NROWS + KEMB) {
      int j = t - NROWS;
      const float* p = emb + (size_t)j * DIM;
      float s0 = np_sumsq_128(p, 1);
      float s1 = np_sumsq_128(p + 128, 1);
      E[j] = s0 + s1;
    }
  } else {
    if (!do_filter) return;
    int u = (blockIdx.x - 144) * 256 + threadIdx.x;   // 0..131071
    int lane = u & 63;
    int ks = (u >> 6) & 7;
    int g16 = u >> 9;
    int j = g16 * 16 + (lane & 15);
    int kb = ks * 32 + (lane >> 4) * 8;
    const float* p = emb + (size_t)j * DIM + kb;
    short out[8];
#pragma unroll
    for (int i = 0; i < 8; ++i) out[i] = (short)f2bf(p[i]);
    *(bf16x8*)(ebuf + (size_t)u * 8) = *(bf16x8*)out;
  }
}

// ---------- fused filter+rescue (R7): R3 filter core + in-kernel chains ----
// Filter core unchanged from R3 (proven ~134 us, jt=4, frag-major LDS A).
// NEW tail phase: candidate lists are already in LDS (cnt_l/cand_l) -> run
// the exact rescue chains HERE (512 thr = 64 rows x 8 chains) instead of a
// separate kernel. Chains read z k-strided from GLOBAL (lines are L2-hot:
// this block just read them in the A-stage) and recompute S via the same
// np_sumsq_128(p,HW_) pairwise tree as original prep -> S, d, (d,j)
// tie-break all bit-identical to the R0-proven exact_cand. Lexicographic
// shfl_xor reduce (masks 1/2/4) within each 8-thread row group.
// Kills: exact_cand launch + cnt/cand global round-trip + its z staging.
// [R4 lesson: tile-skip predicates cost more VALU than they save.]
__global__ __launch_bounds__(512, 3) void filter2_kernel(
    const float* __restrict__ z, const short* __restrict__ ebuf,
    const float* __restrict__ E, const float* __restrict__ emb,
    int* __restrict__ idx_out, float* __restrict__ idxf_out) {
  __shared__ __align__(16) short Ab[32 * 512];   // 32 KB, fragment-major
  __shared__ float rowmin_l[64][8];
  __shared__ float thr_l[64];
  __shared__ int   cnt_l[64];
  __shared__ int   cand_l[64][8];

  const int t = threadIdx.x;
  const int w = t >> 6, lane = t & 63;
  const int quad = lane >> 4, l16 = lane & 15;
  const int nb = blockIdx.x * 64;
  const int b = nb >> 10, hwb = nb & 1023;   // 64 | 1024: no b straddle

  // ---- cooperative A stage: wave w converts k-slice ks=w, mt=0..3 ----
  {
    const float* zb2 = z + (size_t)b * (DIM * HW_) + hwb;
    const int k0 = w * 32 + quad * 8;
#pragma unroll
    for (int mt = 0; mt < 4; ++mt) {
      const int r = mt * 16 + l16;
      short tmp[8];
#pragma unroll
      for (int i = 0; i < 8; ++i)
        tmp[i] = (short)f2bf(zb2[(size_t)(k0 + i) * HW_ + r]);
      *(bf16x8*)(Ab + ((mt * 8 + w) * 64 + lane) * 8) = *(bf16x8*)tmp;
    }
  }
  __syncthreads();

  const f32x4 zero = {0.0f, 0.0f, 0.0f, 0.0f};
  const short* Abl = Ab + lane * 8;          // per-thread frag base

  // ================= sweep 0: row minima =================
  float runmin[4][4];
#pragma unroll
  for (int mt = 0; mt < 4; ++mt)
#pragma unroll
    for (int rg = 0; rg < 4; ++rg) runmin[mt][rg] = 3.0e38f;

#pragma unroll 1
  for (int grp = 0; grp < 8; ++grp) {
    const int jb = w * 512 + grp * 64;
    const int g16b = jb >> 4;
    f32x4 acc[4][4];
#pragma unroll
    for (int jt = 0; jt < 4; ++jt)
#pragma unroll
      for (int mt = 0; mt < 4; ++mt) acc[jt][mt] = zero;
#pragma unroll 1
    for (int ks = 0; ks < 8; ++ks) {
      bf16x8 av[4];
#pragma unroll
      for (int mt = 0; mt < 4; ++mt)
        av[mt] = *(const bf16x8*)(Abl + (mt * 8 + ks) * 512);
#pragma unroll
      for (int jt = 0; jt < 4; ++jt) {
        bf16x8 bfr = *(const bf16x8*)(ebuf +
            ((size_t)(g16b + jt) * 8 + ks) * 512 + lane * 8);
#pragma unroll
        for (int mt = 0; mt < 4; ++mt)
          acc[jt][mt] = __builtin_amdgcn_mfma_f32_16x16x32_bf16(
              av[mt], bfr, acc[jt][mt], 0, 0, 0);
      }
    }
#pragma unroll
    for (int jt = 0; jt < 4; ++jt) {
      float Ej = E[jb + jt * 16 + l16];
#pragma unroll
      for (int mt = 0; mt < 4; ++mt)
#pragma unroll
        for (int rg = 0; rg < 4; ++rg) {
          float g = fmaf(-2.0f, acc[jt][mt][rg], Ej);
          runmin[mt][rg] = fminf(runmin[mt][rg], g);
        }
    }
  }
  // reduce over the 16 j-columns
#pragma unroll
  for (int mt = 0; mt < 4; ++mt)
#pragma unroll
    for (int rg = 0; rg < 4; ++rg) {
      float m = runmin[mt][rg];
#pragma unroll
      for (int mask = 1; mask <= 8; mask <<= 1)
        m = fminf(m, __shfl_xor(m, mask, 64));
      runmin[mt][rg] = m;
    }
  if (l16 == 0) {
#pragma unroll
    for (int mt = 0; mt < 4; ++mt)
#pragma unroll
      for (int rg = 0; rg < 4; ++rg)
        rowmin_l[mt * 16 + quad * 4 + rg][w] = runmin[mt][rg];
  }
  __syncthreads();
  if (t < 64) {
    float m0 = fminf(fminf(rowmin_l[t][0], rowmin_l[t][1]),
                     fminf(rowmin_l[t][2], rowmin_l[t][3]));
    float m1 = fminf(fminf(rowmin_l[t][4], rowmin_l[t][5]),
                     fminf(rowmin_l[t][6], rowmin_l[t][7]));
    thr_l[t] = fminf(m0, m1) + RESCUE_W;
    cnt_l[t] = 0;
  }
  __syncthreads();
  float thrv[4][4];
#pragma unroll
  for (int mt = 0; mt < 4; ++mt)
#pragma unroll
    for (int rg = 0; rg < 4; ++rg)
      thrv[mt][rg] = thr_l[mt * 16 + quad * 4 + rg];

  // ================= sweep 1: emission =================
#pragma unroll 1
  for (int grp = 0; grp < 8; ++grp) {
    const int jb = w * 512 + grp * 64;
    const int g16b = jb >> 4;
    f32x4 acc[4][4];
#pragma unroll
    for (int jt = 0; jt < 4; ++jt)
#pragma unroll
      for (int mt = 0; mt < 4; ++mt) acc[jt][mt] = zero;
#pragma unroll 1
    for (int ks = 0; ks < 8; ++ks) {
      bf16x8 av[4];
#pragma unroll
      for (int mt = 0; mt < 4; ++mt)
        av[mt] = *(const bf16x8*)(Abl + (mt * 8 + ks) * 512);
#pragma unroll
      for (int jt = 0; jt < 4; ++jt) {
        bf16x8 bfr = *(const bf16x8*)(ebuf +
            ((size_t)(g16b + jt) * 8 + ks) * 512 + lane * 8);
#pragma unroll
        for (int mt = 0; mt < 4; ++mt)
          acc[jt][mt] = __builtin_amdgcn_mfma_f32_16x16x32_bf16(
              av[mt], bfr, acc[jt][mt], 0, 0, 0);
      }
    }
#pragma unroll
    for (int jt = 0; jt < 4; ++jt) {
      int jcol = jb + jt * 16 + l16;
      float Ej = E[jcol];
#pragma unroll
      for (int mt = 0; mt < 4; ++mt)
#pragma unroll
        for (int rg = 0; rg < 4; ++rg) {
          float g = fmaf(-2.0f, acc[jt][mt][rg], Ej);
          if (g <= thrv[mt][rg]) {
            int rl = mt * 16 + quad * 4 + rg;
            int slot = atomicAdd(&cnt_l[rl], 1);
            if (slot < 8) cand_l[rl][slot] = jcol;
          }
        }
    }
  }
  __syncthreads();

  // ================= in-kernel rescue chains =================
  {
    const int r = t >> 3, p = t & 7;          // 64 rows x 8 chains
    const int row = nb + r;
    const float* zr = z + (size_t)b * (DIM * HW_) + hwb + r;  // z[k]@zr[k*HW_]
    float s;
    {
      float s0 = np_sumsq_128(zr, HW_);
      float s1 = np_sumsq_128(zr + 128 * HW_, HW_);
      s = s0 + s1;                            // == original prep S[row]
    }
    int c = cnt_l[r];
    float bd = 3.0e38f; int bj = 0x7fffffff;
    if (c <= 8) {
      if (p < c) {
        int j = cand_l[r][p];
        const float* e = emb + (size_t)j * DIM;
        float acc = 0.0f;
#pragma unroll 8
        for (int k4 = 0; k4 < 64; ++k4) {     // sequential k ascending
          float4 ev = *(const float4*)(e + k4 * 4);
          acc = fmaf(zr[(size_t)(k4 * 4 + 0) * HW_], ev.x, acc);
          acc = fmaf(zr[(size_t)(k4 * 4 + 1) * HW_], ev.y, acc);
          acc = fmaf(zr[(size_t)(k4 * 4 + 2) * HW_], ev.z, acc);
          acc = fmaf(zr[(size_t)(k4 * 4 + 3) * HW_], ev.w, acc);
        }
        bd = fmaf(-2.0f, acc, s + E[j]);
        bj = j;
      }
    } else if (p == 0) {
      for (int j = 0; j < KEMB; ++j) {        // overflow fallback (P~0)
        const float* e = emb + (size_t)j * DIM;
        float acc = 0.0f;
        for (int k4 = 0; k4 < 64; ++k4) {
          float4 ev = *(const float4*)(e + k4 * 4);
          acc = fmaf(zr[(size_t)(k4 * 4 + 0) * HW_], ev.x, acc);
          acc = fmaf(zr[(size_t)(k4 * 4 + 1) * HW_], ev.y, acc);
          acc = fmaf(zr[(size_t)(k4 * 4 + 2) * HW_], ev.z, acc);
          acc = fmaf(zr[(size_t)(k4 * 4 + 3) * HW_], ev.w, acc);
        }
        float d = fmaf(-2.0f, acc, s + E[j]);
        if (d < bd || (d == bd && j < bj)) { bd = d; bj = j; }
      }
    }
#pragma unroll
    for (int m = 1; m <= 4; m <<= 1) {        // lexicographic (d,j) reduce
      float od = __shfl_xor(bd, m, 64);
      int   oj = __shfl_xor(bj, m, 64);
      if (od < bd || (od == bd && oj < bj)) { bd = od; bj = oj; }
    }
    if (p == 0) { idx_out[row] = bj; idxf_out[row] = (float)bj; }
  }
}

// ---------- fallback fp32 kernel (R2 version, known-passing) ----------
#define RT 64
#define JT 256
#define KC 16
__global__ __launch_bounds__(256, 2) void dist_argmin_kernel(
    const float* __restrict__ z, const float* __restrict__ emb,
    const float* __restrict__ S, const float* __restrict__ E,
    int* __restrict__ idx_out, float* __restrict__ idxf_out) {
  __shared__ float zt[DIM * RT];
  __shared__ float et[KC * JT];
  const int t  = threadIdx.x;
  const int g  = t & 31;
  const int tr = t >> 5;
  const int nb = blockIdx.x * RT;
  const int b  = nb >> 10;
  const int hwb = nb & 1023;
  const float* zb = z + (size_t)b * (DIM * HW_) + hwb;
#pragma unroll
  for (int i = 0; i < 16; ++i) {
    int flat = t + i * 256;
    int k  = flat >> 4;
    int r4 = flat & 15;
    float4 v = *(const float4*)(zb + (size_t)k * HW_ + r4 * 4);
    *(float4*)(zt + flat * 4) = v;
  }
  float bestd[8];
  int   bestj[8];
#pragma unroll
  for (int i = 0; i < 8; ++i) { bestd[i] = 3.0e38f; bestj[i] = 0; }
  float Sreg[8];
#pragma unroll
  for (int rr = 0; rr < 8; ++rr) Sreg[rr] = S[nb + tr * 8 + rr];
  float4 pf[4];
#pragma unroll
  for (int q = 0; q < 4; ++q) {
    int cid = q * 256 + t;
    pf[q] = *(const float4*)(emb + (size_t)(cid >> 2) * DIM + (cid & 3) * 4);
  }
  for (int jt = 0; jt < KEMB / JT; ++jt) {
    float acc[8][8];
#pragma unroll
    for (int rr = 0; rr < 8; ++rr)
#pragma unroll
      for (int c = 0; c < 8; ++c) acc[rr][c] = 0.0f;
    for (int kc = 0; kc < DIM / KC; ++kc) {
      __syncthreads();
#pragma unroll
      for (int q = 0; q < 4; ++q) {
        int cid = q * 256 + t;
        int j = cid >> 2, k4 = cid & 3;
        et[(k4 * 4 + 0) * JT + j] = pf[q].x;
        et[(k4 * 4 + 1) * JT + j] = pf[q].y;
        et[(k4 * 4 + 2) * JT + j] = pf[q].z;
        et[(k4 * 4 + 3) * JT + j] = pf[q].w;
      }
      int s = jt * (DIM / KC) + kc + 1;
      if (s < (KEMB / JT) * (DIM / KC)) {
        int njt = s >> 4, nkc = s & 15;
        const float* base = emb + (size_t)njt * JT * DIM + nkc * KC;
#pragma unroll
        for (int q = 0; q < 4; ++q) {
          int cid = q * 256 + t;
          pf[q] = *(const float4*)(base + (size_t)(cid >> 2) * DIM + (cid & 3) * 4);
        }
      }
      __syncthreads();
      const float* ztk = zt + (kc * KC) * RT;
#pragma unroll
      for (int kk = 0; kk < KC; ++kk) {
        float4 z0 = *(const float4*)(ztk + kk * RT + tr * 8);
        float4 z1 = *(const float4*)(ztk + kk * RT + tr * 8 + 4);
        float2 e0 = *(const float2*)(et + kk * JT + g * 2);
        float2 e1 = *(const float2*)(et + kk * JT + 64 + g * 2);
        float2 e2 = *(const float2*)(et + kk * JT + 128 + g * 2);
        float2 e3 = *(const float2*)(et + kk * JT + 192 + g * 2);
        float zr[8] = {z0.x, z0.y, z0.z, z0.w, z1.x, z1.y, z1.z, z1.w};
        float ev[8] = {e0.x, e0.y, e1.x, e1.y, e2.x, e2.y, e3.x, e3.y};
#pragma unroll
        for (int rr = 0; rr < 8; ++rr)
#pragma unroll
          for (int c = 0; c < 8; ++c)
            acc[rr][c] = fmaf(zr[rr], ev[c], acc[rr][c]);
      }
    }
    int jb = jt * JT;
    float Ereg[8];
#pragma unroll
    for (int c = 0; c < 8; ++c)
      Ereg[c] = E[jb + (c >> 1) * 64 + g * 2 + (c & 1)];
#pragma unroll
    for (int rr = 0; rr < 8; ++rr)
#pragma unroll
      for (int c = 0; c < 8; ++c) {
        float A = Sreg[rr] + Ereg[c];
        float d = fmaf(-2.0f, acc[rr][c], A);
        int j = jb + (c >> 1) * 64 + g * 2 + (c & 1);
        if (d < bestd[rr] || (d == bestd[rr] && j < bestj[rr])) {
          bestd[rr] = d; bestj[rr] = j;
        }
      }
  }
  __syncthreads();
  float* rd = et;
  int*   rj = (int*)(et + 2048);
#pragma unroll
  for (int rr = 0; rr < 8; ++rr) {
    rd[(tr * 8 + rr) * 32 + g] = bestd[rr];
    rj[(tr * 8 + rr) * 32 + g] = bestj[rr];
  }
  __syncthreads();
  if (t < RT) {
    float bd = rd[t * 32];
    int   bj = rj[t * 32];
    for (int c = 1; c < 32; ++c) {
      float d2 = rd[t * 32 + c];
      int   j2 = rj[t * 32 + c];
      if (d2 < bd || (d2 == bd && j2 < bj)) { bd = d2; bj = j2; }
    }
    idx_out[nb + t]  = bj;
    idxf_out[nb + t] = (float)bj;
  }
}

// ---------- epilogue v3: 32 rows/block (33 KB LDS -> 4 blocks/CU) ----------
// Same proven gather + STE math as the 64-row epilogue; thread map:
// rr = t&31 (hw), dq = t>>5, d = dc*8+dq -> 128B write segments.
#define EROWS 32
#define EPAD 257
__global__ __launch_bounds__(256) void epilogue_kernel(
    const float* __restrict__ z, const float* __restrict__ emb,
    const int* __restrict__ idx, float* __restrict__ out0,
    double* __restrict__ loss_sum, int* __restrict__ done,
    float* __restrict__ out_loss) {
#pragma clang fp contract(off)
  __shared__ float eq[EROWS * EPAD];
  __shared__ int   iv_l[EROWS];
  __shared__ double wsum[4];
  const int t = threadIdx.x, w = t >> 6, lane = t & 63;
  const int nb = blockIdx.x * EROWS;
  const int b = nb >> 10, hwb = nb & 1023;   // 32 | 1024: no b straddle

  if (t < EROWS) iv_l[t] = idx[nb + t];
  __syncthreads();
  const float4* emb4 = (const float4*)emb;
#pragma unroll
  for (int i = 0; i < 8; ++i) {
    int r = w * 8 + i;
    float4 v = emb4[(size_t)iv_l[r] * 64 + lane];
    *(float4*)(eq + r * EPAD + lane * 4) = v;
  }
  __syncthreads();

  double acc = 0.0;
  {
    const int rr = t & 31, dq = t >> 5;      // dq 0..7
    const float* zb = z + (size_t)b * (DIM * HW_) + hwb + rr;
    float* ob = out0 + (size_t)b * (DIM * HW_) + hwb + rr;
    const float* zqr = eq + rr * EPAD;
    for (int dc = 0; dc < 32; ++dc) {
      int d = dc * 8 + dq;
      float zp = zb[(size_t)d * HW_];
      float zq = zqr[d];
      float td = zq - zp;                    // fl(z_q - zp)
      ob[(size_t)d * HW_] = zp + td;         // fl(zp + fl(z_q - zp))
      acc += (double)(td * td);
    }
  }
#pragma unroll
  for (int off = 32; off > 0; off >>= 1) acc += __shfl_down(acc, off, 64);
  if (lane == 0) wsum[w] = acc;
  __syncthreads();
  if (t == 0) {
    double bsum = (wsum[0] + wsum[1]) + (wsum[2] + wsum[3]);
    atomicAdd(loss_sum, bsum);
    __threadfence();
    int prev = atomicAdd(done, 1);
    if (prev == 1023) {
      double m = loss_sum[0] / 8388608.0;
      float mf = (float)m;
      float bb = 10.0f * mf;
      out_loss[0] = mf + bb;
    }
  }
}

extern "C" void kernel_launch(void* const* d_in, const int* in_sizes, int n_in,
                              void* d_out, int out_size, void* d_ws, size_t ws_size,
                              hipStream_t stream) {
  const float* z   = (const float*)d_in[0];
  const float* emb = (const float*)d_in[1];
  float* out = (float*)d_out;
  char* ws = (char*)d_ws;
  int*      idx  = (int*)ws;
  float*    S    = (float*)(ws + WS_S_OFF);
  float*    E    = (float*)(ws + WS_E_OFF);
  double*   ls   = (double*)(ws + WS_LOSS_OFF);
  int*      done = (int*)(ws + WS_DONE_OFF);
  short*    ebuf = (short*)(ws + WS_EBUF_OFF);

  const int do_filter = (ws_size >= (size_t)WS_NEEDED) ? 1 : 0;

  prep_kernel<<<656, 256, 0, stream>>>(z, emb, S, E, ebuf, ls, done, do_filter);

  if (do_filter) {
    filter2_kernel<<<512, 512, 0, stream>>>(z, ebuf, E, emb, idx,
                                            out + 8388609);
  } else {
    dist_argmin_kernel<<<NROWS / RT, 256, 0, stream>>>(z, emb, S, E, idx,
                                                       out + 8388609);
  }

  epilogue_kernel<<<1024, 256, 0, stream>>>(z, emb, idx, out, ls, done,
                                            out + 8388608);
}

// Round 8
// 278.198 us; speedup vs baseline: 1.0391x; 1.0391x over previous
//
#include <hip/hip_runtime.h>

#define DIM   256
#define HW_   1024
#define NROWS 32768
#define KEMB  4096

// ---------------- ws layout ----------------
// [0,       131072)  int    idx[32768]
// [131072,  262144)  float  S[32768]     (fallback path only)
// [262144,  278528)  float  E[4096]
// [278528,  278536)  double loss_sum
// [278536,  278540)  int    done
// [278592,  409664)  int    cnt[32768]
// [540736,  1589312) int    cand[32768][8]
// [1589312, 3686464) short  ebuf[1048576]  (bf16, 16x16-frag-major, 2 MB)
#define WS_S_OFF    131072
#define WS_E_OFF    262144
#define WS_LOSS_OFF 278528
#define WS_DONE_OFF 278536
#define WS_CNT_OFF  278592
#define WS_CAND_OFF 540736
#define WS_EBUF_OFF 1589312
#define WS_NEEDED   3686464
#define RESCUE_W    1.5e-4f

typedef __attribute__((ext_vector_type(8))) short bf16x8;
typedef __attribute__((ext_vector_type(4))) float f32x4;

__device__ __forceinline__ unsigned short f2bf(float v) {
  unsigned u = __float_as_uint(v);
  return (unsigned short)((u + 0x7FFFu + ((u >> 16) & 1u)) >> 16);
}

// ---------- numpy-pairwise row sums of squares ----------
__device__ __forceinline__ float np_sumsq_128(const float* q, int stride) {
#pragma clang fp contract(off)
  float r[8];
#pragma unroll
  for (int i = 0; i < 8; ++i) { float v = q[i * stride]; r[i] = v * v; }
  for (int blk = 8; blk < 128; blk += 8) {
#pragma unroll
    for (int i = 0; i < 8; ++i) {
      float v = q[(blk + i) * stride];
      float sq = v * v;
      r[i] = r[i] + sq;
    }
  }
  return ((r[0] + r[1]) + (r[2] + r[3])) + ((r[4] + r[5]) + (r[6] + r[7]));
}

// ---------- prep v2: init + E norms (+S only on fallback path) + pack ------
__global__ __launch_bounds__(256) void prep_kernel(
    const float* __restrict__ z, const float* __restrict__ emb,
    float* __restrict__ S, float* __restrict__ E, short* __restrict__ ebuf,
    double* __restrict__ loss_sum, int* __restrict__ done, int do_filter) {
#pragma clang fp contract(off)
  if (blockIdx.x < 144) {
    int t = blockIdx.x * 256 + threadIdx.x;
    if (t == 0) { loss_sum[0] = 0.0; done[0] = 0; }
    if (t < NROWS) {
      if (!do_filter) {
        int b = t >> 10, hw = t & 1023;
        const float* p = z + (size_t)b * (DIM * HW_) + hw;
        float s0 = np_sumsq_128(p, HW_);
        float s1 = np_sumsq_128(p + 128 * HW_, HW_);
        S[t] = s0 + s1;
      }
    } else if (t < NROWS + KEMB) {
      int j = t - NROWS;
      const float* p = emb + (size_t)j * DIM;
      float s0 = np_sumsq_128(p, 1);
      float s1 = np_sumsq_128(p + 128, 1);
      E[j] = s0 + s1;
    }
  } else {
    if (!do_filter) return;
    int u = (blockIdx.x - 144) * 256 + threadIdx.x;   // 0..131071
    int lane = u & 63;
    int ks = (u >> 6) & 7;
    int g16 = u >> 9;
    int j = g16 * 16 + (lane & 15);
    int kb = ks * 32 + (lane >> 4) * 8;
    const float* p = emb + (size_t)j * DIM + kb;
    short out[8];
#pragma unroll
    for (int i = 0; i < 8; ++i) out[i] = (short)f2bf(p[i]);
    *(bf16x8*)(ebuf + (size_t)u * 8) = *(bf16x8*)out;
  }
}

// ---------- fused filter (R3-proven, ~134 us): jt=4, frag-major LDS A ------
// [R4 lesson: tile-skip predicates cost more VALU than they save.]
// [R7 lesson: do NOT fold rescue chains in here - z is L2-cold after the
// sweeps; chains re-fetch from HBM serialized at the block tail (+33 us).]
__global__ __launch_bounds__(512, 3) void filter2_kernel(
    const float* __restrict__ z, const short* __restrict__ ebuf,
    const float* __restrict__ E, int* __restrict__ cnt_g,
    int* __restrict__ cand_g) {
  __shared__ __align__(16) short Ab[32 * 512];   // 32 KB, fragment-major
  __shared__ float rowmin_l[64][8];
  __shared__ float thr_l[64];
  __shared__ int   cnt_l[64];
  __shared__ int   cand_l[64][8];

  const int t = threadIdx.x;
  const int w = t >> 6, lane = t & 63;
  const int quad = lane >> 4, l16 = lane & 15;
  const int nb = blockIdx.x * 64;
  const int b = nb >> 10, hwb = nb & 1023;   // 64 | 1024: no b straddle

  // ---- cooperative A stage: wave w converts k-slice ks=w, mt=0..3 ----
  {
    const float* zb2 = z + (size_t)b * (DIM * HW_) + hwb;
    const int k0 = w * 32 + quad * 8;
#pragma unroll
    for (int mt = 0; mt < 4; ++mt) {
      const int r = mt * 16 + l16;
      short tmp[8];
#pragma unroll
      for (int i = 0; i < 8; ++i)
        tmp[i] = (short)f2bf(zb2[(size_t)(k0 + i) * HW_ + r]);
      *(bf16x8*)(Ab + ((mt * 8 + w) * 64 + lane) * 8) = *(bf16x8*)tmp;
    }
  }
  __syncthreads();

  const f32x4 zero = {0.0f, 0.0f, 0.0f, 0.0f};
  const short* Abl = Ab + lane * 8;          // per-thread frag base

  // ================= sweep 0: row minima =================
  float runmin[4][4];
#pragma unroll
  for (int mt = 0; mt < 4; ++mt)
#pragma unroll
    for (int rg = 0; rg < 4; ++rg) runmin[mt][rg] = 3.0e38f;

#pragma unroll 1
  for (int grp = 0; grp < 8; ++grp) {
    const int jb = w * 512 + grp * 64;
    const int g16b = jb >> 4;
    f32x4 acc[4][4];
#pragma unroll
    for (int jt = 0; jt < 4; ++jt)
#pragma unroll
      for (int mt = 0; mt < 4; ++mt) acc[jt][mt] = zero;
#pragma unroll 1
    for (int ks = 0; ks < 8; ++ks) {
      bf16x8 av[4];
#pragma unroll
      for (int mt = 0; mt < 4; ++mt)
        av[mt] = *(const bf16x8*)(Abl + (mt * 8 + ks) * 512);
#pragma unroll
      for (int jt = 0; jt < 4; ++jt) {
        bf16x8 bfr = *(const bf16x8*)(ebuf +
            ((size_t)(g16b + jt) * 8 + ks) * 512 + lane * 8);
#pragma unroll
        for (int mt = 0; mt < 4; ++mt)
          acc[jt][mt] = __builtin_amdgcn_mfma_f32_16x16x32_bf16(
              av[mt], bfr, acc[jt][mt], 0, 0, 0);
      }
    }
#pragma unroll
    for (int jt = 0; jt < 4; ++jt) {
      float Ej = E[jb + jt * 16 + l16];
#pragma unroll
      for (int mt = 0; mt < 4; ++mt)
#pragma unroll
        for (int rg = 0; rg < 4; ++rg) {
          float g = fmaf(-2.0f, acc[jt][mt][rg], Ej);
          runmin[mt][rg] = fminf(runmin[mt][rg], g);
        }
    }
  }
  // reduce over the 16 j-columns
#pragma unroll
  for (int mt = 0; mt < 4; ++mt)
#pragma unroll
    for (int rg = 0; rg < 4; ++rg) {
      float m = runmin[mt][rg];
#pragma unroll
      for (int mask = 1; mask <= 8; mask <<= 1)
        m = fminf(m, __shfl_xor(m, mask, 64));
      runmin[mt][rg] = m;
    }
  if (l16 == 0) {
#pragma unroll
    for (int mt = 0; mt < 4; ++mt)
#pragma unroll
      for (int rg = 0; rg < 4; ++rg)
        rowmin_l[mt * 16 + quad * 4 + rg][w] = runmin[mt][rg];
  }
  __syncthreads();
  if (t < 64) {
    float m0 = fminf(fminf(rowmin_l[t][0], rowmin_l[t][1]),
                     fminf(rowmin_l[t][2], rowmin_l[t][3]));
    float m1 = fminf(fminf(rowmin_l[t][4], rowmin_l[t][5]),
                     fminf(rowmin_l[t][6], rowmin_l[t][7]));
    thr_l[t] = fminf(m0, m1) + RESCUE_W;
    cnt_l[t] = 0;
  }
  __syncthreads();
  float thrv[4][4];
#pragma unroll
  for (int mt = 0; mt < 4; ++mt)
#pragma unroll
    for (int rg = 0; rg < 4; ++rg)
      thrv[mt][rg] = thr_l[mt * 16 + quad * 4 + rg];

  // ================= sweep 1: emission =================
#pragma unroll 1
  for (int grp = 0; grp < 8; ++grp) {
    const int jb = w * 512 + grp * 64;
    const int g16b = jb >> 4;
    f32x4 acc[4][4];
#pragma unroll
    for (int jt = 0; jt < 4; ++jt)
#pragma unroll
      for (int mt = 0; mt < 4; ++mt) acc[jt][mt] = zero;
#pragma unroll 1
    for (int ks = 0; ks < 8; ++ks) {
      bf16x8 av[4];
#pragma unroll
      for (int mt = 0; mt < 4; ++mt)
        av[mt] = *(const bf16x8*)(Abl + (mt * 8 + ks) * 512);
#pragma unroll
      for (int jt = 0; jt < 4; ++jt) {
        bf16x8 bfr = *(const bf16x8*)(ebuf +
            ((size_t)(g16b + jt) * 8 + ks) * 512 + lane * 8);
#pragma unroll
        for (int mt = 0; mt < 4; ++mt)
          acc[jt][mt] = __builtin_amdgcn_mfma_f32_16x16x32_bf16(
              av[mt], bfr, acc[jt][mt], 0, 0, 0);
      }
    }
#pragma unroll
    for (int jt = 0; jt < 4; ++jt) {
      int jcol = jb + jt * 16 + l16;
      float Ej = E[jcol];
#pragma unroll
      for (int mt = 0; mt < 4; ++mt)
#pragma unroll
        for (int rg = 0; rg < 4; ++rg) {
          float g = fmaf(-2.0f, acc[jt][mt][rg], Ej);
          if (g <= thrv[mt][rg]) {
            int rl = mt * 16 + quad * 4 + rg;
            int slot = atomicAdd(&cnt_l[rl], 1);
            if (slot < 8) cand_l[rl][slot] = jcol;
          }
        }
    }
  }
  __syncthreads();
  if (t < 64) {
    int c = cnt_l[t];
    cnt_g[nb + t] = c;
    int cc = c > 8 ? 8 : c;
    for (int p = 0; p < cc; ++p) cand_g[(size_t)(nb + t) * 8 + p] = cand_l[t][p];
  }
}

// ---------- rescue v3: LDS-staged z + PARALLEL chains (8/row) ----------
// 1024 blocks x 32 rows x 8 chains (all 256 threads active; R5's version
// idled 192/256 threads and ran chains serially -> dependent-FMA latency).
// z staged once to LDS (FPAD=257 -> conflict-free); S recomputed in numpy
// pairwise order (bit-identical, R6-verified); lexicographic (d,j)
// shfl_xor reduce over masks 1/2/4 (R6-verified). LDS 33 KB -> 4 blk/CU.
#define FROWS 32
#define FPAD 257
__global__ __launch_bounds__(256) void exact_cand_kernel(
    const float* __restrict__ z, const float* __restrict__ emb,
    const float* __restrict__ E,
    const int* __restrict__ cnt_g, const int* __restrict__ cand_g,
    int* __restrict__ idx_out, float* __restrict__ idxf_out) {
#pragma clang fp contract(off)
  __shared__ float z_l[FROWS * FPAD];
  const int t = threadIdx.x;
  const int nb = blockIdx.x * FROWS;
  const int b = nb >> 10, hwb = nb & 1023;   // 32 | 1024: no b straddle
  const float* zb = z + (size_t)b * (DIM * HW_) + hwb;

  // ---- stage z tile [32 rows][256 k] -> z_l[row*FPAD + k] ----
#pragma unroll
  for (int i = 0; i < 8; ++i) {
    int f = i * 256 + t;                 // 0..2047
    int k = f >> 3, r4 = f & 7;
    float4 v = *(const float4*)(zb + (size_t)k * HW_ + r4 * 4);
    z_l[(r4 * 4 + 0) * FPAD + k] = v.x;
    z_l[(r4 * 4 + 1) * FPAD + k] = v.y;
    z_l[(r4 * 4 + 2) * FPAD + k] = v.z;
    z_l[(r4 * 4 + 3) * FPAD + k] = v.w;
  }
  __syncthreads();

  const int r = t >> 3, p = t & 7;
  const int row = nb + r;
  const float* zrow = z_l + r * FPAD;
  float s;
  {
    float s0 = np_sumsq_128(zrow, 1);
    float s1 = np_sumsq_128(zrow + 128, 1);
    s = s0 + s1;
  }
  int c = cnt_g[row];
  float bd = 3.0e38f; int bj = 0x7fffffff;
  if (c <= 8) {
    if (p < c) {
      int j = cand_g[(size_t)row * 8 + p];
      const float* e = emb + (size_t)j * DIM;
      float acc = 0.0f;
#pragma unroll 8
      for (int k4 = 0; k4 < 64; ++k4) {        // sequential k ascending
        float4 ev = *(const float4*)(e + k4 * 4);
        acc = fmaf(zrow[k4 * 4 + 0], ev.x, acc);
        acc = fmaf(zrow[k4 * 4 + 1], ev.y, acc);
        acc = fmaf(zrow[k4 * 4 + 2], ev.z, acc);
        acc = fmaf(zrow[k4 * 4 + 3], ev.w, acc);
      }
      bd = fmaf(-2.0f, acc, s + E[j]);
      bj = j;
    }
  } else if (p == 0) {
    for (int j = 0; j < KEMB; ++j) {           // overflow fallback (P~0)
      const float* e = emb + (size_t)j * DIM;
      float acc = 0.0f;
      for (int k4 = 0; k4 < 64; ++k4) {
        float4 ev = *(const float4*)(e + k4 * 4);
        acc = fmaf(zrow[k4 * 4 + 0], ev.x, acc);
        acc = fmaf(zrow[k4 * 4 + 1], ev.y, acc);
        acc = fmaf(zrow[k4 * 4 + 2], ev.z, acc);
        acc = fmaf(zrow[k4 * 4 + 3], ev.w, acc);
      }
      float d = fmaf(-2.0f, acc, s + E[j]);
      if (d < bd || (d == bd && j < bj)) { bd = d; bj = j; }
    }
  }
#pragma unroll
  for (int m = 1; m <= 4; m <<= 1) {           // lexicographic (d,j) reduce
    float od = __shfl_xor(bd, m, 64);
    int   oj = __shfl_xor(bj, m, 64);
    if (od < bd || (od == bd && oj < bj)) { bd = od; bj = oj; }
  }
  if (p == 0) { idx_out[row] = bj; idxf_out[row] = (float)bj; }
}

// ---------- fallback fp32 kernel (R2 version, known-passing) ----------
#define RT 64
#define JT 256
#define KC 16
__global__ __launch_bounds__(256, 2) void dist_argmin_kernel(
    const float* __restrict__ z, const float* __restrict__ emb,
    const float* __restrict__ S, const float* __restrict__ E,
    int* __restrict__ idx_out, float* __restrict__ idxf_out) {
  __shared__ float zt[DIM * RT];
  __shared__ float et[KC * JT];
  const int t  = threadIdx.x;
  const int g  = t & 31;
  const int tr = t >> 5;
  const int nb = blockIdx.x * RT;
  const int b  = nb >> 10;
  const int hwb = nb & 1023;
  const float* zb = z + (size_t)b * (DIM * HW_) + hwb;
#pragma unroll
  for (int i = 0; i < 16; ++i) {
    int flat = t + i * 256;
    int k  = flat >> 4;
    int r4 = flat & 15;
    float4 v = *(const float4*)(zb + (size_t)k * HW_ + r4 * 4);
    *(float4*)(zt + flat * 4) = v;
  }
  float bestd[8];
  int   bestj[8];
#pragma unroll
  for (int i = 0; i < 8; ++i) { bestd[i] = 3.0e38f; bestj[i] = 0; }
  float Sreg[8];
#pragma unroll
  for (int rr = 0; rr < 8; ++rr) Sreg[rr] = S[nb + tr * 8 + rr];
  float4 pf[4];
#pragma unroll
  for (int q = 0; q < 4; ++q) {
    int cid = q * 256 + t;
    pf[q] = *(const float4*)(emb + (size_t)(cid >> 2) * DIM + (cid & 3) * 4);
  }
  for (int jt = 0; jt < KEMB / JT; ++jt) {
    float acc[8][8];
#pragma unroll
    for (int rr = 0; rr < 8; ++rr)
#pragma unroll
      for (int c = 0; c < 8; ++c) acc[rr][c] = 0.0f;
    for (int kc = 0; kc < DIM / KC; ++kc) {
      __syncthreads();
#pragma unroll
      for (int q = 0; q < 4; ++q) {
        int cid = q * 256 + t;
        int j = cid >> 2, k4 = cid & 3;
        et[(k4 * 4 + 0) * JT + j] = pf[q].x;
        et[(k4 * 4 + 1) * JT + j] = pf[q].y;
        et[(k4 * 4 + 2) * JT + j] = pf[q].z;
        et[(k4 * 4 + 3) * JT + j] = pf[q].w;
      }
      int s = jt * (DIM / KC) + kc + 1;
      if (s < (KEMB / JT) * (DIM / KC)) {
        int njt = s >> 4, nkc = s & 15;
        const float* base = emb + (size_t)njt * JT * DIM + nkc * KC;
#pragma unroll
        for (int q = 0; q < 4; ++q) {
          int cid = q * 256 + t;
          pf[q] = *(const float4*)(base + (size_t)(cid >> 2) * DIM + (cid & 3) * 4);
        }
      }
      __syncthreads();
      const float* ztk = zt + (kc * KC) * RT;
#pragma unroll
      for (int kk = 0; kk < KC; ++kk) {
        float4 z0 = *(const float4*)(ztk + kk * RT + tr * 8);
        float4 z1 = *(const float4*)(ztk + kk * RT + tr * 8 + 4);
        float2 e0 = *(const float2*)(et + kk * JT + g * 2);
        float2 e1 = *(const float2*)(et + kk * JT + 64 + g * 2);
        float2 e2 = *(const float2*)(et + kk * JT + 128 + g * 2);
        float2 e3 = *(const float2*)(et + kk * JT + 192 + g * 2);
        float zr[8] = {z0.x, z0.y, z0.z, z0.w, z1.x, z1.y, z1.z, z1.w};
        float ev[8] = {e0.x, e0.y, e1.x, e1.y, e2.x, e2.y, e3.x, e3.y};
#pragma unroll
        for (int rr = 0; rr < 8; ++rr)
#pragma unroll
          for (int c = 0; c < 8; ++c)
            acc[rr][c] = fmaf(zr[rr], ev[c], acc[rr][c]);
      }
    }
    int jb = jt * JT;
    float Ereg[8];
#pragma unroll
    for (int c = 0; c < 8; ++c)
      Ereg[c] = E[jb + (c >> 1) * 64 + g * 2 + (c & 1)];
#pragma unroll
    for (int rr = 0; rr < 8; ++rr)
#pragma unroll
      for (int c = 0; c < 8; ++c) {
        float A = Sreg[rr] + Ereg[c];
        float d = fmaf(-2.0f, acc[rr][c], A);
        int j = jb + (c >> 1) * 64 + g * 2 + (c & 1);
        if (d < bestd[rr] || (d == bestd[rr] && j < bestj[rr])) {
          bestd[rr] = d; bestj[rr] = j;
        }
      }
  }
  __syncthreads();
  float* rd = et;
  int*   rj = (int*)(et + 2048);
#pragma unroll
  for (int rr = 0; rr < 8; ++rr) {
    rd[(tr * 8 + rr) * 32 + g] = bestd[rr];
    rj[(tr * 8 + rr) * 32 + g] = bestj[rr];
  }
  __syncthreads();
  if (t < RT) {
    float bd = rd[t * 32];
    int   bj = rj[t * 32];
    for (int c = 1; c < 32; ++c) {
      float d2 = rd[t * 32 + c];
      int   j2 = rj[t * 32 + c];
      if (d2 < bd || (d2 == bd && j2 < bj)) { bd = d2; bj = j2; }
    }
    idx_out[nb + t]  = bj;
    idxf_out[nb + t] = (float)bj;
  }
}

// ---------- epilogue v3 (R7-verified): 32 rows/block, 4 blocks/CU ----------
#define EROWS 32
#define EPAD 257
__global__ __launch_bounds__(256) void epilogue_kernel(
    const float* __restrict__ z, const float* __restrict__ emb,
    const int* __restrict__ idx, float* __restrict__ out0,
    double* __restrict__ loss_sum, int* __restrict__ done,
    float* __restrict__ out_loss) {
#pragma clang fp contract(off)
  __shared__ float eq[EROWS * EPAD];
  __shared__ int   iv_l[EROWS];
  __shared__ double wsum[4];
  const int t = threadIdx.x, w = t >> 6, lane = t & 63;
  const int nb = blockIdx.x * EROWS;
  const int b = nb >> 10, hwb = nb & 1023;   // 32 | 1024: no b straddle

  if (t < EROWS) iv_l[t] = idx[nb + t];
  __syncthreads();
  const float4* emb4 = (const float4*)emb;
#pragma unroll
  for (int i = 0; i < 8; ++i) {
    int r = w * 8 + i;
    float4 v = emb4[(size_t)iv_l[r] * 64 + lane];
    *(float4*)(eq + r * EPAD + lane * 4) = v;
  }
  __syncthreads();

  double acc = 0.0;
  {
    const int rr = t & 31, dq = t >> 5;      // dq 0..7
    const float* zb = z + (size_t)b * (DIM * HW_) + hwb + rr;
    float* ob = out0 + (size_t)b * (DIM * HW_) + hwb + rr;
    const float* zqr = eq + rr * EPAD;
    for (int dc = 0; dc < 32; ++dc) {
      int d = dc * 8 + dq;
      float zp = zb[(size_t)d * HW_];
      float zq = zqr[d];
      float td = zq - zp;                    // fl(z_q - zp)
      ob[(size_t)d * HW_] = zp + td;         // fl(zp + fl(z_q - zp))
      acc += (double)(td * td);
    }
  }
#pragma unroll
  for (int off = 32; off > 0; off >>= 1) acc += __shfl_down(acc, off, 64);
  if (lane == 0) wsum[w] = acc;
  __syncthreads();
  if (t == 0) {
    double bsum = (wsum[0] + wsum[1]) + (wsum[2] + wsum[3]);
    atomicAdd(loss_sum, bsum);
    __threadfence();
    int prev = atomicAdd(done, 1);
    if (prev == 1023) {
      double m = loss_sum[0] / 8388608.0;
      float mf = (float)m;
      float bb = 10.0f * mf;
      out_loss[0] = mf + bb;
    }
  }
}

extern "C" void kernel_launch(void* const* d_in, const int* in_sizes, int n_in,
                              void* d_out, int out_size, void* d_ws, size_t ws_size,
                              hipStream_t stream) {
  const float* z   = (const float*)d_in[0];
  const float* emb = (const float*)d_in[1];
  float* out = (float*)d_out;
  char* ws = (char*)d_ws;
  int*      idx  = (int*)ws;
  float*    S    = (float*)(ws + WS_S_OFF);
  float*    E    = (float*)(ws + WS_E_OFF);
  double*   ls   = (double*)(ws + WS_LOSS_OFF);
  int*      done = (int*)(ws + WS_DONE_OFF);
  int*      cnt  = (int*)(ws + WS_CNT_OFF);
  int*      cand = (int*)(ws + WS_CAND_OFF);
  short*    ebuf = (short*)(ws + WS_EBUF_OFF);

  const int do_filter = (ws_size >= (size_t)WS_NEEDED) ? 1 : 0;

  prep_kernel<<<656, 256, 0, stream>>>(z, emb, S, E, ebuf, ls, done, do_filter);

  if (do_filter) {
    filter2_kernel<<<512, 512, 0, stream>>>(z, ebuf, E, cnt, cand);
    exact_cand_kernel<<<1024, 256, 0, stream>>>(z, emb, E, cnt, cand, idx,
                                                out + 8388609);
  } else {
    dist_argmin_kernel<<<NROWS / RT, 256, 0, stream>>>(z, emb, S, E, idx,
                                                       out + 8388609);
  }

  epilogue_kernel<<<1024, 256, 0, stream>>>(z, emb, idx, out, ls, done,
                                            out + 8388608);
}

// Round 9
// 254.647 us; speedup vs baseline: 1.1352x; 1.0925x over previous
//
#include <hip/hip_runtime.h>

#define DIM   256
#define HW_   1024
#define NROWS 32768
#define KEMB  4096

// ---------------- ws layout ----------------
// [0,       131072)  int    idx[32768]
// [131072,  262144)  float  S[32768]   (fallback path only)
// [262144,  278528)  float  E[4096]
// [278528,  278536)  double loss_sum
// [278536,  278540)  int    done
// [278592,  409664)  int    cnt[32768]
// [540736,  1589312) int    cand[32768][8]
// [1589312, 3686464) short  ebuf[1048576]  (bf16, 16x16-frag-major, 2 MB)
#define WS_S_OFF    131072
#define WS_E_OFF    262144
#define WS_LOSS_OFF 278528
#define WS_DONE_OFF 278536
#define WS_CNT_OFF  278592
#define WS_CAND_OFF 540736
#define WS_EBUF_OFF 1589312
#define WS_NEEDED   3686464
#define RESCUE_W    1.5e-4f

typedef __attribute__((ext_vector_type(8))) short bf16x8;
typedef __attribute__((ext_vector_type(4))) float f32x4;

__device__ __forceinline__ unsigned short f2bf(float v) {
  unsigned u = __float_as_uint(v);
  return (unsigned short)((u + 0x7FFFu + ((u >> 16) & 1u)) >> 16);
}

// ---------- numpy-pairwise row sums of squares ----------
__device__ __forceinline__ float np_sumsq_128(const float* q, int stride) {
#pragma clang fp contract(off)
  float r[8];
#pragma unroll
  for (int i = 0; i < 8; ++i) { float v = q[i * stride]; r[i] = v * v; }
  for (int blk = 8; blk < 128; blk += 8) {
#pragma unroll
    for (int i = 0; i < 8; ++i) {
      float v = q[(blk + i) * stride];
      float sq = v * v;
      r[i] = r[i] + sq;
    }
  }
  return ((r[0] + r[1]) + (r[2] + r[3])) + ((r[4] + r[5]) + (r[6] + r[7]));
}

// ---------- prep v2: init + E norms (+S only on fallback path) + pack ------
// Filter path no longer needs S (exact_cand recomputes it bit-identically
// from its LDS-staged z tile) -> skip the z read entirely.
__global__ __launch_bounds__(256) void prep_kernel(
    const float* __restrict__ z, const float* __restrict__ emb,
    float* __restrict__ S, float* __restrict__ E, short* __restrict__ ebuf,
    double* __restrict__ loss_sum, int* __restrict__ done, int do_filter) {
#pragma clang fp contract(off)
  if (blockIdx.x < 144) {
    int t = blockIdx.x * 256 + threadIdx.x;
    if (t == 0) { loss_sum[0] = 0.0; done[0] = 0; }
    if (t < NROWS) {
      if (!do_filter) {
        int b = t >> 10, hw = t & 1023;
        const float* p = z + (size_t)b * (DIM * HW_) + hw;
        float s0 = np_sumsq_128(p, HW_);
        float s1 = np_sumsq_128(p + 128 * HW_, HW_);
        S[t] = s0 + s1;
      }
    } else if (t < NROWS + KEMB) {
      int j = t - NROWS;
      const float* p = emb + (size_t)j * DIM;
      float s0 = np_sumsq_128(p, 1);
      float s1 = np_sumsq_128(p + 128, 1);
      E[j] = s0 + s1;
    }
  } else {
    if (!do_filter) return;
    int u = (blockIdx.x - 144) * 256 + threadIdx.x;   // 0..131071
    int lane = u & 63;
    int ks = (u >> 6) & 7;
    int g16 = u >> 9;
    int j = g16 * 16 + (lane & 15);
    int kb = ks * 32 + (lane >> 4) * 8;
    const float* p = emb + (size_t)j * DIM + kb;
    short out[8];
#pragma unroll
    for (int i = 0; i < 8; ++i) out[i] = (short)f2bf(p[i]);
    *(bf16x8*)(ebuf + (size_t)u * 8) = *(bf16x8*)out;
  }
}

// ---------- fused filter (R3-proven, ~134 us): jt=4, frag-major LDS A ------
// [R4 lesson: tile-skip predicates cost more VALU than they save.]
// [R7 lesson: do NOT fold rescue chains in here - z is L2-cold after the
// sweeps; chains re-fetch from HBM serialized at the block tail (+33 us).]
__global__ __launch_bounds__(512, 3) void filter2_kernel(
    const float* __restrict__ z, const short* __restrict__ ebuf,
    const float* __restrict__ E, int* __restrict__ cnt_g,
    int* __restrict__ cand_g) {
  __shared__ __align__(16) short Ab[32 * 512];   // 32 KB, fragment-major
  __shared__ float rowmin_l[64][8];
  __shared__ float thr_l[64];
  __shared__ int   cnt_l[64];
  __shared__ int   cand_l[64][8];

  const int t = threadIdx.x;
  const int w = t >> 6, lane = t & 63;
  const int quad = lane >> 4, l16 = lane & 15;
  const int nb = blockIdx.x * 64;
  const int b = nb >> 10, hwb = nb & 1023;   // 64 | 1024: no b straddle

  // ---- cooperative A stage: wave w converts k-slice ks=w, mt=0..3 ----
  {
    const float* zb2 = z + (size_t)b * (DIM * HW_) + hwb;
    const int k0 = w * 32 + quad * 8;
#pragma unroll
    for (int mt = 0; mt < 4; ++mt) {
      const int r = mt * 16 + l16;
      short tmp[8];
#pragma unroll
      for (int i = 0; i < 8; ++i)
        tmp[i] = (short)f2bf(zb2[(size_t)(k0 + i) * HW_ + r]);
      *(bf16x8*)(Ab + ((mt * 8 + w) * 64 + lane) * 8) = *(bf16x8*)tmp;
    }
  }
  __syncthreads();

  const f32x4 zero = {0.0f, 0.0f, 0.0f, 0.0f};
  const short* Abl = Ab + lane * 8;          // per-thread frag base

  // ================= sweep 0: row minima =================
  float runmin[4][4];
#pragma unroll
  for (int mt = 0; mt < 4; ++mt)
#pragma unroll
    for (int rg = 0; rg < 4; ++rg) runmin[mt][rg] = 3.0e38f;

#pragma unroll 1
  for (int grp = 0; grp < 8; ++grp) {
    const int jb = w * 512 + grp * 64;
    const int g16b = jb >> 4;
    f32x4 acc[4][4];
#pragma unroll
    for (int jt = 0; jt < 4; ++jt)
#pragma unroll
      for (int mt = 0; mt < 4; ++mt) acc[jt][mt] = zero;
#pragma unroll 1
    for (int ks = 0; ks < 8; ++ks) {
      bf16x8 av[4];
#pragma unroll
      for (int mt = 0; mt < 4; ++mt)
        av[mt] = *(const bf16x8*)(Abl + (mt * 8 + ks) * 512);
#pragma unroll
      for (int jt = 0; jt < 4; ++jt) {
        bf16x8 bfr = *(const bf16x8*)(ebuf +
            ((size_t)(g16b + jt) * 8 + ks) * 512 + lane * 8);
#pragma unroll
        for (int mt = 0; mt < 4; ++mt)
          acc[jt][mt] = __builtin_amdgcn_mfma_f32_16x16x32_bf16(
              av[mt], bfr, acc[jt][mt], 0, 0, 0);
      }
    }
#pragma unroll
    for (int jt = 0; jt < 4; ++jt) {
      float Ej = E[jb + jt * 16 + l16];
#pragma unroll
      for (int mt = 0; mt < 4; ++mt)
#pragma unroll
        for (int rg = 0; rg < 4; ++rg) {
          float g = fmaf(-2.0f, acc[jt][mt][rg], Ej);
          runmin[mt][rg] = fminf(runmin[mt][rg], g);
        }
    }
  }
  // reduce over the 16 j-columns
#pragma unroll
  for (int mt = 0; mt < 4; ++mt)
#pragma unroll
    for (int rg = 0; rg < 4; ++rg) {
      float m = runmin[mt][rg];
#pragma unroll
      for (int mask = 1; mask <= 8; mask <<= 1)
        m = fminf(m, __shfl_xor(m, mask, 64));
      runmin[mt][rg] = m;
    }
  if (l16 == 0) {
#pragma unroll
    for (int mt = 0; mt < 4; ++mt)
#pragma unroll
      for (int rg = 0; rg < 4; ++rg)
        rowmin_l[mt * 16 + quad * 4 + rg][w] = runmin[mt][rg];
  }
  __syncthreads();
  if (t < 64) {
    float m0 = fminf(fminf(rowmin_l[t][0], rowmin_l[t][1]),
                     fminf(rowmin_l[t][2], rowmin_l[t][3]));
    float m1 = fminf(fminf(rowmin_l[t][4], rowmin_l[t][5]),
                     fminf(rowmin_l[t][6], rowmin_l[t][7]));
    thr_l[t] = fminf(m0, m1) + RESCUE_W;
    cnt_l[t] = 0;
  }
  __syncthreads();
  float thrv[4][4];
#pragma unroll
  for (int mt = 0; mt < 4; ++mt)
#pragma unroll
    for (int rg = 0; rg < 4; ++rg)
      thrv[mt][rg] = thr_l[mt * 16 + quad * 4 + rg];

  // ================= sweep 1: emission =================
#pragma unroll 1
  for (int grp = 0; grp < 8; ++grp) {
    const int jb = w * 512 + grp * 64;
    const int g16b = jb >> 4;
    f32x4 acc[4][4];
#pragma unroll
    for (int jt = 0; jt < 4; ++jt)
#pragma unroll
      for (int mt = 0; mt < 4; ++mt) acc[jt][mt] = zero;
#pragma unroll 1
    for (int ks = 0; ks < 8; ++ks) {
      bf16x8 av[4];
#pragma unroll
      for (int mt = 0; mt < 4; ++mt)
        av[mt] = *(const bf16x8*)(Abl + (mt * 8 + ks) * 512);
#pragma unroll
      for (int jt = 0; jt < 4; ++jt) {
        bf16x8 bfr = *(const bf16x8*)(ebuf +
            ((size_t)(g16b + jt) * 8 + ks) * 512 + lane * 8);
#pragma unroll
        for (int mt = 0; mt < 4; ++mt)
          acc[jt][mt] = __builtin_amdgcn_mfma_f32_16x16x32_bf16(
              av[mt], bfr, acc[jt][mt], 0, 0, 0);
      }
    }
#pragma unroll
    for (int jt = 0; jt < 4; ++jt) {
      int jcol = jb + jt * 16 + l16;
      float Ej = E[jcol];
#pragma unroll
      for (int mt = 0; mt < 4; ++mt)
#pragma unroll
        for (int rg = 0; rg < 4; ++rg) {
          float g = fmaf(-2.0f, acc[jt][mt][rg], Ej);
          if (g <= thrv[mt][rg]) {
            int rl = mt * 16 + quad * 4 + rg;
            int slot = atomicAdd(&cnt_l[rl], 1);
            if (slot < 8) cand_l[rl][slot] = jcol;
          }
        }
    }
  }
  __syncthreads();
  if (t < 64) {
    int c = cnt_l[t];
    cnt_g[nb + t] = c;
    int cc = c > 8 ? 8 : c;
    for (int p = 0; p < cc; ++p) cand_g[(size_t)(nb + t) * 8 + p] = cand_l[t][p];
  }
}

// ---------- rescue v2.1: R5 staging + 4-parallel chains per row ----------
// IDENTICAL to the R5-proven exact_cand (512 blocks, 64-row z tile,
// XPAD=257 conflict-free staging) except the chain phase: r=t>>2, p=t&3 ->
// 4 chains/row, all 256 threads active (R5 idled 192 and ran chains
// serially). Thread p takes candidates q = p, p+4 (same per-candidate
// math, same set); lexicographic (d,j) shfl_xor reduce over masks 1,2
// within the 4-lane row group (pattern HW-verified in R6/R8, absmax 0).
#define XPAD 257
__global__ __launch_bounds__(256, 2) void exact_cand_kernel(
    const float* __restrict__ z, const float* __restrict__ emb,
    const float* __restrict__ E,
    const int* __restrict__ cnt_g, const int* __restrict__ cand_g,
    int* __restrict__ idx_out, float* __restrict__ idxf_out) {
#pragma clang fp contract(off)
  __shared__ float z_l[64 * XPAD];
  const int t = threadIdx.x;
  const int nb = blockIdx.x * 64;
  const int b = nb >> 10, hwb = nb & 1023;   // 64 | 1024: no b straddle
  const float* zb = z + (size_t)b * (DIM * HW_) + hwb;
#pragma unroll
  for (int i = 0; i < 16; ++i) {
    int flat = i * 256 + t;
    int d = flat >> 4, r4 = flat & 15;
    float4 v = *(const float4*)(zb + (size_t)d * HW_ + r4 * 4);
    z_l[(r4 * 4 + 0) * XPAD + d] = v.x;
    z_l[(r4 * 4 + 1) * XPAD + d] = v.y;
    z_l[(r4 * 4 + 2) * XPAD + d] = v.z;
    z_l[(r4 * 4 + 3) * XPAD + d] = v.w;
  }
  __syncthreads();

  const int r = t >> 2, p = t & 3;           // 64 rows x 4 chains
  const int row = nb + r;
  const float* zrow = z_l + r * XPAD;        // z[k] at zrow[k], bit-identical
  float s;
  {
    float s0 = np_sumsq_128(zrow, 1);
    float s1 = np_sumsq_128(zrow + 128, 1);
    s = s0 + s1;
  }
  int c = cnt_g[row];
  float bd = 3.0e38f; int bj = 0x7fffffff;
  if (c <= 8) {
    for (int q = p; q < c; q += 4) {
      int j = cand_g[(size_t)row * 8 + q];
      const float* e = emb + (size_t)j * DIM;
      float acc = 0.0f;
#pragma unroll 8
      for (int k4 = 0; k4 < 64; ++k4) {        // sequential k ascending
        float4 ev = *(const float4*)(e + k4 * 4);
        acc = fmaf(zrow[k4 * 4 + 0], ev.x, acc);
        acc = fmaf(zrow[k4 * 4 + 1], ev.y, acc);
        acc = fmaf(zrow[k4 * 4 + 2], ev.z, acc);
        acc = fmaf(zrow[k4 * 4 + 3], ev.w, acc);
      }
      float d = fmaf(-2.0f, acc, s + E[j]);
      if (d < bd || (d == bd && j < bj)) { bd = d; bj = j; }
    }
  } else if (p == 0) {
    for (int j = 0; j < KEMB; ++j) {           // overflow fallback (P~0)
      const float* e = emb + (size_t)j * DIM;
      float acc = 0.0f;
      for (int k4 = 0; k4 < 64; ++k4) {
        float4 ev = *(const float4*)(e + k4 * 4);
        acc = fmaf(zrow[k4 * 4 + 0], ev.x, acc);
        acc = fmaf(zrow[k4 * 4 + 1], ev.y, acc);
        acc = fmaf(zrow[k4 * 4 + 2], ev.z, acc);
        acc = fmaf(zrow[k4 * 4 + 3], ev.w, acc);
      }
      float d = fmaf(-2.0f, acc, s + E[j]);
      if (d < bd || (d == bd && j < bj)) { bd = d; bj = j; }
    }
  }
#pragma unroll
  for (int m = 1; m <= 2; m <<= 1) {           // lexicographic (d,j) reduce
    float od = __shfl_xor(bd, m, 64);
    int   oj = __shfl_xor(bj, m, 64);
    if (od < bd || (od == bd && oj < bj)) { bd = od; bj = oj; }
  }
  if (p == 0) { idx_out[row] = bj; idxf_out[row] = (float)bj; }
}

// ---------- fallback fp32 kernel (R2 version, known-passing) ----------
#define RT 64
#define JT 256
#define KC 16
__global__ __launch_bounds__(256, 2) void dist_argmin_kernel(
    const float* __restrict__ z, const float* __restrict__ emb,
    const float* __restrict__ S, const float* __restrict__ E,
    int* __restrict__ idx_out, float* __restrict__ idxf_out) {
  __shared__ float zt[DIM * RT];
  __shared__ float et[KC * JT];
  const int t  = threadIdx.x;
  const int g  = t & 31;
  const int tr = t >> 5;
  const int nb = blockIdx.x * RT;
  const int b  = nb >> 10;
  const int hwb = nb & 1023;
  const float* zb = z + (size_t)b * (DIM * HW_) + hwb;
#pragma unroll
  for (int i = 0; i < 16; ++i) {
    int flat = t + i * 256;
    int k  = flat >> 4;
    int r4 = flat & 15;
    float4 v = *(const float4*)(zb + (size_t)k * HW_ + r4 * 4);
    *(float4*)(zt + flat * 4) = v;
  }
  float bestd[8];
  int   bestj[8];
#pragma unroll
  for (int i = 0; i < 8; ++i) { bestd[i] = 3.0e38f; bestj[i] = 0; }
  float Sreg[8];
#pragma unroll
  for (int rr = 0; rr < 8; ++rr) Sreg[rr] = S[nb + tr * 8 + rr];
  float4 pf[4];
#pragma unroll
  for (int q = 0; q < 4; ++q) {
    int cid = q * 256 + t;
    pf[q] = *(const float4*)(emb + (size_t)(cid >> 2) * DIM + (cid & 3) * 4);
  }
  for (int jt = 0; jt < KEMB / JT; ++jt) {
    float acc[8][8];
#pragma unroll
    for (int rr = 0; rr < 8; ++rr)
#pragma unroll
      for (int c = 0; c < 8; ++c) acc[rr][c] = 0.0f;
    for (int kc = 0; kc < DIM / KC; ++kc) {
      __syncthreads();
#pragma unroll
      for (int q = 0; q < 4; ++q) {
        int cid = q * 256 + t;
        int j = cid >> 2, k4 = cid & 3;
        et[(k4 * 4 + 0) * JT + j] = pf[q].x;
        et[(k4 * 4 + 1) * JT + j] = pf[q].y;
        et[(k4 * 4 + 2) * JT + j] = pf[q].z;
        et[(k4 * 4 + 3) * JT + j] = pf[q].w;
      }
      int s = jt * (DIM / KC) + kc + 1;
      if (s < (KEMB / JT) * (DIM / KC)) {
        int njt = s >> 4, nkc = s & 15;
        const float* base = emb + (size_t)njt * JT * DIM + nkc * KC;
#pragma unroll
        for (int q = 0; q < 4; ++q) {
          int cid = q * 256 + t;
          pf[q] = *(const float4*)(base + (size_t)(cid >> 2) * DIM + (cid & 3) * 4);
        }
      }
      __syncthreads();
      const float* ztk = zt + (kc * KC) * RT;
#pragma unroll
      for (int kk = 0; kk < KC; ++kk) {
        float4 z0 = *(const float4*)(ztk + kk * RT + tr * 8);
        float4 z1 = *(const float4*)(ztk + kk * RT + tr * 8 + 4);
        float2 e0 = *(const float2*)(et + kk * JT + g * 2);
        float2 e1 = *(const float2*)(et + kk * JT + 64 + g * 2);
        float2 e2 = *(const float2*)(et + kk * JT + 128 + g * 2);
        float2 e3 = *(const float2*)(et + kk * JT + 192 + g * 2);
        float zr[8] = {z0.x, z0.y, z0.z, z0.w, z1.x, z1.y, z1.z, z1.w};
        float ev[8] = {e0.x, e0.y, e1.x, e1.y, e2.x, e2.y, e3.x, e3.y};
#pragma unroll
        for (int rr = 0; rr < 8; ++rr)
#pragma unroll
          for (int c = 0; c < 8; ++c)
            acc[rr][c] = fmaf(zr[rr], ev[c], acc[rr][c]);
      }
    }
    int jb = jt * JT;
    float Ereg[8];
#pragma unroll
    for (int c = 0; c < 8; ++c)
      Ereg[c] = E[jb + (c >> 1) * 64 + g * 2 + (c & 1)];
#pragma unroll
    for (int rr = 0; rr < 8; ++rr)
#pragma unroll
      for (int c = 0; c < 8; ++c) {
        float A = Sreg[rr] + Ereg[c];
        float d = fmaf(-2.0f, acc[rr][c], A);
        int j = jb + (c >> 1) * 64 + g * 2 + (c & 1);
        if (d < bestd[rr] || (d == bestd[rr] && j < bestj[rr])) {
          bestd[rr] = d; bestj[rr] = j;
        }
      }
  }
  __syncthreads();
  float* rd = et;
  int*   rj = (int*)(et + 2048);
#pragma unroll
  for (int rr = 0; rr < 8; ++rr) {
    rd[(tr * 8 + rr) * 32 + g] = bestd[rr];
    rj[(tr * 8 + rr) * 32 + g] = bestj[rr];
  }
  __syncthreads();
  if (t < RT) {
    float bd = rd[t * 32];
    int   bj = rj[t * 32];
    for (int c = 1; c < 32; ++c) {
      float d2 = rd[t * 32 + c];
      int   j2 = rj[t * 32 + c];
      if (d2 < bd || (d2 == bd && j2 < bj)) { bd = d2; bj = j2; }
    }
    idx_out[nb + t]  = bj;
    idxf_out[nb + t] = (float)bj;
  }
}

// ---------- epilogue v2 (R5-proven): LDS-staged gather + STE + loss ----------
#define EPAD 257
__global__ __launch_bounds__(256) void epilogue_kernel(
    const float* __restrict__ z, const float* __restrict__ emb,
    const int* __restrict__ idx, float* __restrict__ out0,
    double* __restrict__ loss_sum, int* __restrict__ done,
    float* __restrict__ out_loss) {
#pragma clang fp contract(off)
  __shared__ float eq[64 * EPAD];
  __shared__ int   iv_l[64];
  __shared__ double wsum[4];
  const int t = threadIdx.x, w = t >> 6, lane = t & 63;
  const int nb = blockIdx.x * 64;
  const int b = nb >> 10, hwb = nb & 1023;

  if (t < 64) iv_l[t] = idx[nb + t];
  __syncthreads();
  const float4* emb4 = (const float4*)emb;
#pragma unroll
  for (int i = 0; i < 16; ++i) {
    int r = w * 16 + i;
    float4 v = emb4[(size_t)iv_l[r] * 64 + lane];
    *(float4*)(eq + r * EPAD + lane * 4) = v;
  }
  __syncthreads();

  double acc = 0.0;
  const float* zb = z + (size_t)b * (DIM * HW_) + hwb;
  float* ob = out0 + (size_t)b * (DIM * HW_) + hwb;
  for (int dc = 0; dc < 64; ++dc) {
    int d = dc * 4 + w;
    float zp = zb[(size_t)d * HW_ + lane];
    float zq = eq[lane * EPAD + d];
    float td = zq - zp;                   // fl(z_q - zp)
    ob[(size_t)d * HW_ + lane] = zp + td; // fl(zp + fl(z_q - zp))
    acc += (double)(td * td);
  }
#pragma unroll
  for (int off = 32; off > 0; off >>= 1) acc += __shfl_down(acc, off, 64);
  if (lane == 0) wsum[w] = acc;
  __syncthreads();
  if (t == 0) {
    double bsum = (wsum[0] + wsum[1]) + (wsum[2] + wsum[3]);
    atomicAdd(loss_sum, bsum);
    __threadfence();
    int prev = atomicAdd(done, 1);
    if (prev == 511) {
      double m = loss_sum[0] / 8388608.0;
      float mf = (float)m;
      float bb = 10.0f * mf;
      out_loss[0] = mf + bb;
    }
  }
}

extern "C" void kernel_launch(void* const* d_in, const int* in_sizes, int n_in,
                              void* d_out, int out_size, void* d_ws, size_t ws_size,
                              hipStream_t stream) {
  const float* z   = (const float*)d_in[0];
  const float* emb = (const float*)d_in[1];
  float* out = (float*)d_out;
  char* ws = (char*)d_ws;
  int*      idx  = (int*)ws;
  float*    S    = (float*)(ws + WS_S_OFF);
  float*    E    = (float*)(ws + WS_E_OFF);
  double*   ls   = (double*)(ws + WS_LOSS_OFF);
  int*      done = (int*)(ws + WS_DONE_OFF);
  int*      cnt  = (int*)(ws + WS_CNT_OFF);
  int*      cand = (int*)(ws + WS_CAND_OFF);
  short*    ebuf = (short*)(ws + WS_EBUF_OFF);

  const int do_filter = (ws_size >= (size_t)WS_NEEDED) ? 1 : 0;

  prep_kernel<<<656, 256, 0, stream>>>(z, emb, S, E, ebuf, ls, done, do_filter);

  if (do_filter) {
    filter2_kernel<<<512, 512, 0, stream>>>(z, ebuf, E, cnt, cand);
    exact_cand_kernel<<<512, 256, 0, stream>>>(z, emb, E, cnt, cand, idx,
                                               out + 8388609);
  } else {
    dist_argmin_kernel<<<NROWS / RT, 256, 0, stream>>>(z, emb, S, E, idx,
                                                       out + 8388609);
  }

  epilogue_kernel<<<512, 256, 0, stream>>>(z, emb, idx, out, ls, done,
                                           out + 8388608);
}